// Round 5
// baseline (407.336 us; speedup 1.0000x reference)
//
#include <hip/hip_runtime.h>
#include <hip/hip_bf16.h>

// SimpleMHA, all-TN bf16 MFMA GEMMs. 256x256 tile, BK=32, 4-buffer depth-3
// software pipeline with counted s_waitcnt vmcnt(N) (T3+T4), XOR bank swizzle
// via pre-swizzled global source (T2), s_setprio around MFMA cluster (T5).
// B=4, S=2048, D=1024, scale 1/32 applied in the score GEMM epilogue.

typedef __attribute__((ext_vector_type(8))) __bf16 bf16x8;
typedef __attribute__((ext_vector_type(4))) float f32x4;
typedef __attribute__((ext_vector_type(8))) unsigned short u16x8;
typedef __attribute__((ext_vector_type(4))) float float4v;
typedef long long ll;

static __device__ __forceinline__ unsigned short f2b(float f) {
  unsigned int u = __float_as_uint(f);
  u += 0x7fffu + ((u >> 16) & 1u);
  return (unsigned short)(u >> 16);
}
static __device__ __forceinline__ float b2f(unsigned short b) {
  return __uint_as_float(((unsigned int)b) << 16);
}

static __device__ __forceinline__ void gload16(const unsigned short* g, unsigned short* l) {
  // 16B direct global->LDS. LDS dest = wave-uniform base + lane*16 (HW rule).
  __builtin_amdgcn_global_load_lds(
      (const __attribute__((address_space(1))) void*)g,
      (__attribute__((address_space(3))) void*)l, 16, 0, 0);
}

__global__ __launch_bounds__(256) void cvt_f32_bf16(const float* __restrict__ in,
                                                    unsigned short* __restrict__ out,
                                                    long long n) {
  long long i = ((long long)blockIdx.x * 256 + threadIdx.x) * 8;
  if (i + 8 > n) return;
  float4v a = *(const float4v*)(in + i);
  float4v b = *(const float4v*)(in + i + 4);
  u16x8 o;
  o[0] = f2b(a[0]); o[1] = f2b(a[1]); o[2] = f2b(a[2]); o[3] = f2b(a[3]);
  o[4] = f2b(b[0]); o[5] = f2b(b[1]); o[6] = f2b(b[2]); o[7] = f2b(b[3]);
  *(u16x8*)(out + i) = o;
}

// out[c][r] = bf16(in[r][c]) for n x n f32 input. Block (32,8), 32x32 tiles.
__global__ __launch_bounds__(256) void transpose_cvt(const float* __restrict__ in,
                                                     unsigned short* __restrict__ out, int n) {
  __shared__ float t[32][33];
  int bx = blockIdx.x * 32, by = blockIdx.y * 32;
  int tx = threadIdx.x, ty = threadIdx.y;
#pragma unroll
  for (int i = 0; i < 32; i += 8)
    t[ty + i][tx] = in[(ll)(by + ty + i) * n + bx + tx];
  __syncthreads();
#pragma unroll
  for (int i = 0; i < 32; i += 8)
    out[(ll)(bx + ty + i) * n + by + tx] = f2b(t[tx][ty + i]);
}

__global__ void concat2(const float* __restrict__ a, const float* __restrict__ b,
                        float* __restrict__ o, int n) {
  int i = blockIdx.x * 256 + threadIdx.x;
  if (i < n) { o[i] = a[i]; o[i + n] = b[i]; }
}

// C = alpha*(A @ B^T + bias). A:[M,K] lda, B:[N,K] ldb, both bf16 k-contiguous.
// 256x256 tile, BK=32, 8 waves (2Mx4N, each 128x64 out). 4 LDS buffers, stage
// tile t+3 while computing tile t; steady-state vmcnt(8) = 2 tiles in flight.
// Bank swizzle: 16B slot s of row r holds global k-group s^(r&3); applied on
// the GLOBAL source at stage time and on the ds_read address (involution).
// CAUSAL: 0 dense; 1 scores (skip tiles with bcol>brow); 2 PV (Keff=brow+256).
template <int CAUSAL>
__global__ __launch_bounds__(512, 2) void gemm_tn(
    const unsigned short* __restrict__ A, const unsigned short* __restrict__ B,
    const float* __restrict__ bias, void* __restrict__ C,
    int K, int lda, int ldb, int ldc,
    ll strideA, ll strideB, ll strideC,
    float alpha, int c_is_bf16, int bias_row) {
  if (CAUSAL == 1 && blockIdx.x > blockIdx.y) return;

  // 4 bufs x (A 256x32 + B 256x32) bf16 = 4 x 32KB = 128KB
  __shared__ unsigned short smem[4 * 16384];

  const int tid = threadIdx.x;
  const int wid = tid >> 6, lane = tid & 63;
  const int wm = wid >> 2, wn = wid & 3;  // 2 x 4 wave grid
  const int lr = lane & 15, lk = lane >> 4;
  const int bz = blockIdx.z;
  const unsigned short* Ab = A + (ll)bz * strideA;
  const unsigned short* Bb = B + (ll)bz * strideB;
  const int brow = blockIdx.y * 256, bcol = blockIdx.x * 256;

  const int Keff = (CAUSAL == 2) ? (brow + 256) : K;
  const int nt = Keff >> 5;  // BK=32 tiles; always >= 8 here

  f32x4 acc[8][4];
#pragma unroll
  for (int m = 0; m < 8; ++m)
#pragma unroll
    for (int n = 0; n < 4; ++n) acc[m][n] = (f32x4){0.f, 0.f, 0.f, 0.f};

  // Stage K-tile t into buf t&3. Per thread: 2 A chunks + 2 B chunks (wave-
  // uniform LDS dest, per-lane global addr). 1 chunk = 1KB = 16 rows of 64B.
  auto STAGE = [&](int t) {
    unsigned short* lds = &smem[0] + (t & 3) * 16384;
    const int kb = t << 5;
#pragma unroll
    for (int h = 0; h < 2; ++h) {
      const int c = wid * 2 + h;                 // chunk 0..15
      const int row = c * 16 + (lane >> 2);      // tile row 0..255
      const int kg = (lane & 3) ^ (row & 3);     // swizzled 16B k-group
      gload16(Ab + (ll)(brow + row) * lda + kb + kg * 8, lds + c * 512);
      gload16(Bb + (ll)(bcol + row) * ldb + kb + kg * 8, lds + 8192 + c * 512);
    }
  };

  auto COMPUTE = [&](int t) {
    const unsigned short* lds = &smem[0] + (t & 3) * 16384;
    bf16x8 a[8], b[4];
#pragma unroll
    for (int n = 0; n < 4; ++n) {
      const int row = wn * 64 + n * 16 + lr;
      const int slot = lk ^ (row & 3);
      b[n] = *(const bf16x8*)(lds + 8192 + row * 32 + slot * 8);
    }
#pragma unroll
    for (int m = 0; m < 8; ++m) {
      const int row = wm * 128 + m * 16 + lr;
      const int slot = lk ^ (row & 3);
      a[m] = *(const bf16x8*)(lds + row * 32 + slot * 8);
    }
    __builtin_amdgcn_s_setprio(1);
#pragma unroll
    for (int m = 0; m < 8; ++m)
#pragma unroll
      for (int n = 0; n < 4; ++n)
        acc[m][n] = __builtin_amdgcn_mfma_f32_16x16x32_bf16(a[m], b[n], acc[m][n], 0, 0, 0);
    __builtin_amdgcn_s_setprio(0);
  };

  // Prologue: 3 tiles in flight.
  STAGE(0); STAGE(1); STAGE(2);
  // Main: wait tile t (keep 2 tiles outstanding), stage t+3, compute t.
  for (int t = 0; t < nt - 2; ++t) {
    asm volatile("s_waitcnt vmcnt(8)" ::: "memory");
    __builtin_amdgcn_s_barrier();
    if (t + 3 < nt) STAGE(t + 3);
    COMPUTE(t);
  }
  asm volatile("s_waitcnt vmcnt(4)" ::: "memory");
  __builtin_amdgcn_s_barrier();
  COMPUTE(nt - 2);
  asm volatile("s_waitcnt vmcnt(0)" ::: "memory");
  __builtin_amdgcn_s_barrier();
  COMPUTE(nt - 1);

  // C/D layout: col=lane&15, row=(lane>>4)*4+reg (m89-verified)
  ll cbase = (ll)bz * strideC;
#pragma unroll
  for (int m = 0; m < 8; ++m) {
    const int row0 = brow + wm * 128 + m * 16 + lk * 4;
#pragma unroll
    for (int n = 0; n < 4; ++n) {
      const int col = bcol + wn * 64 + n * 16 + lr;
#pragma unroll
      for (int r = 0; r < 4; ++r) {
        float bvv = bias ? (bias_row ? bias[row0 + r] : bias[col]) : 0.0f;
        float v = (acc[m][n][r] + bvv) * alpha;
        ll idx = cbase + (ll)(row0 + r) * ldc + col;
        if (c_is_bf16) ((unsigned short*)C)[idx] = f2b(v);
        else ((float*)C)[idx] = v;
      }
    }
  }
}

// One-pass causal softmax for rows of exactly 2048 bf16. One block per row;
// each thread owns one u16x8. Masked cols written as exact 0.
__global__ __launch_bounds__(256) void softmax_row2048(unsigned short* __restrict__ S) {
  const int r = blockIdx.x, b = blockIdx.y;
  unsigned short* row = S + ((ll)b * 2048 + r) * 2048;
  const int tid = threadIdx.x;
  const int i0 = tid * 8;
  __shared__ float red[4];

  u16x8 v = *(const u16x8*)(row + i0);
  float f[8];
  float m = -3.0e38f;
#pragma unroll
  for (int j = 0; j < 8; ++j) {
    f[j] = (i0 + j <= r) ? b2f(v[j]) : -3.0e38f;
    m = fmaxf(m, f[j]);
  }
#pragma unroll
  for (int o = 1; o < 64; o <<= 1) m = fmaxf(m, __shfl_xor(m, o, 64));
  if ((tid & 63) == 0) red[tid >> 6] = m;
  __syncthreads();
  m = fmaxf(fmaxf(red[0], red[1]), fmaxf(red[2], red[3]));
  __syncthreads();

  float e[8];
  float s = 0.0f;
#pragma unroll
  for (int j = 0; j < 8; ++j) {
    e[j] = (i0 + j <= r) ? __expf(f[j] - m) : 0.0f;
    s += e[j];
  }
#pragma unroll
  for (int o = 1; o < 64; o <<= 1) s += __shfl_xor(s, o, 64);
  if ((tid & 63) == 0) red[tid >> 6] = s;
  __syncthreads();
  s = red[0] + red[1] + red[2] + red[3];
  float inv = 1.0f / s;
  u16x8 o8;
#pragma unroll
  for (int j = 0; j < 8; ++j) o8[j] = f2b(e[j] * inv);
  *(u16x8*)(row + i0) = o8;
}

extern "C" void kernel_launch(void* const* d_in, const int* in_sizes, int n_in,
                              void* d_out, int out_size, void* d_ws, size_t ws_size,
                              hipStream_t stream) {
  const float* x  = (const float*)d_in[0];
  const float* Wq = (const float*)d_in[1];
  const float* bq = (const float*)d_in[2];
  const float* Wk = (const float*)d_in[3];
  const float* bk = (const float*)d_in[4];
  const float* Wv = (const float*)d_in[5];
  const float* bv = (const float*)d_in[6];
  const float* Wo = (const float*)d_in[7];
  const float* bo = (const float*)d_in[8];

  const int B = 4, S = 2048, D = 1024;
  const ll MS = (ll)B * S;  // 8192

  char* p = (char*)d_ws;
  unsigned short* xb   = (unsigned short*)p; p += MS * D * 2;              // 16.8 MB
  unsigned short* Wqkt = (unsigned short*)p; p += (ll)2 * D * D * 2;       // 4.2 MB: [Wq^T; Wk^T]
  unsigned short* Wvt  = (unsigned short*)p; p += (ll)D * D * 2;           // Wv^T
  unsigned short* Wot  = (unsigned short*)p; p += (ll)D * D * 2;           // Wo^T
  float*          bqkc = (float*)p;          p += 2 * D * 4;               // [bq; bk]
  unsigned short* QKc  = (unsigned short*)p; p += MS * 2 * D * 2;          // 33.6 MB: [Q | K]
  unsigned short* Vt   = (unsigned short*)p; p += (ll)D * MS * 2;          // 16.8 MB: V^T [D, MS]
  unsigned short* Sm   = (unsigned short*)p; p += (ll)B * S * S * 2;       // 33.6 MB
  unsigned short* At   = (unsigned short*)p; p += MS * D * 2;              // 16.8 MB

  dim3 blk(256);
  dim3 blk512(512);
  dim3 tblk(32, 8);

  cvt_f32_bf16<<<dim3(4096), blk, 0, stream>>>(x, xb, MS * D);
  transpose_cvt<<<dim3(32, 32), tblk, 0, stream>>>(Wq, Wqkt, D);
  transpose_cvt<<<dim3(32, 32), tblk, 0, stream>>>(Wk, Wqkt + (ll)D * D, D);
  transpose_cvt<<<dim3(32, 32), tblk, 0, stream>>>(Wv, Wvt, D);
  transpose_cvt<<<dim3(32, 32), tblk, 0, stream>>>(Wo, Wot, D);
  concat2<<<dim3(4), blk, 0, stream>>>(bq, bk, bqkc, D);

  // Fused Q|K projection: C[8192, 2048] = x @ [Wq|Wk] + [bq|bk]
  gemm_tn<0><<<dim3(8, 32, 1), blk512, 0, stream>>>(
      xb, Wqkt, bqkc, QKc, D, D, D, 2 * D, 0, 0, 0, 1.0f, 1, 0);

  // V^T [1024, 8192] = Wv^T @ x^T + bv (row bias)
  gemm_tn<0><<<dim3(32, 4, 1), blk512, 0, stream>>>(
      Wvt, xb, bv, Vt, D, D, D, (int)MS, 0, 0, 0, 1.0f, 1, 1);

  // Scores: Sm[b] = (Q_b @ K_b^T) / 32, upper tiles skipped
  gemm_tn<1><<<dim3(8, 8, 4), blk512, 0, stream>>>(
      QKc, QKc + D, nullptr, Sm, D, 2 * D, 2 * D, S,
      (ll)S * 2 * D, (ll)S * 2 * D, (ll)S * S, 0.03125f, 1, 0);

  softmax_row2048<<<dim3(S, B), blk, 0, stream>>>(Sm);

  // PV: At[b] = P_b @ V_b, K-loop limited to brow+256 (causal zeros beyond)
  gemm_tn<2><<<dim3(4, 8, 4), blk512, 0, stream>>>(
      Sm, Vt, nullptr, At, S, S, (int)MS, D,
      (ll)S * S, (ll)S, (ll)S * D, 1.0f, 1, 0);

  // out = At @ Wo + bo (f32)
  gemm_tn<0><<<dim3(4, 32, 1), blk512, 0, stream>>>(
      At, Wot, bo, d_out, D, D, D, D, 0, 0, 0, 1.0f, 0, 0);
}

// Round 7
// 340.661 us; speedup vs baseline: 1.1957x; 1.1957x over previous
//
#include <hip/hip_runtime.h>
#include <hip/hip_bf16.h>

// SimpleMHA. Workhorse: 128x128 2-phase double-buffered GEMM (verified r3).
// New: 256x256 8-phase-style pipelined GEMM (BK=32, counted vmcnt, T2+T3+T4+T5)
// for the two GEMMs whose grids fill the GPU (QK-proj 256 blocks, scores 144).
// B=4, S=2048, D=1024, scale 1/32 in the score epilogue.

typedef __attribute__((ext_vector_type(8))) __bf16 bf16x8;
typedef __attribute__((ext_vector_type(4))) float f32x4;
typedef __attribute__((ext_vector_type(8))) unsigned short u16x8;
typedef __attribute__((ext_vector_type(4))) float float4v;
typedef long long ll;

static __device__ __forceinline__ unsigned short f2b(float f) {
  unsigned int u = __float_as_uint(f);
  u += 0x7fffu + ((u >> 16) & 1u);
  return (unsigned short)(u >> 16);
}
static __device__ __forceinline__ float b2f(unsigned short b) {
  return __uint_as_float(((unsigned int)b) << 16);
}

static __device__ __forceinline__ void gload16(const unsigned short* g, unsigned short* l) {
  // 16B direct global->LDS. LDS dest = wave-uniform base + lane*16 (HW rule).
  __builtin_amdgcn_global_load_lds(
      (const __attribute__((address_space(1))) void*)g,
      (__attribute__((address_space(3))) void*)l, 16, 0, 0);
}

__global__ __launch_bounds__(256) void cvt_f32_bf16(const float* __restrict__ in,
                                                    unsigned short* __restrict__ out,
                                                    long long n) {
  long long i = ((long long)blockIdx.x * 256 + threadIdx.x) * 8;
  if (i + 8 > n) return;
  float4v a = *(const float4v*)(in + i);
  float4v b = *(const float4v*)(in + i + 4);
  u16x8 o;
  o[0] = f2b(a[0]); o[1] = f2b(a[1]); o[2] = f2b(a[2]); o[3] = f2b(a[3]);
  o[4] = f2b(b[0]); o[5] = f2b(b[1]); o[6] = f2b(b[2]); o[7] = f2b(b[3]);
  *(u16x8*)(out + i) = o;
}

// out[c][r] = bf16(in[r][c]) for n x n f32 input. Block (32,8), 32x32 tiles.
__global__ __launch_bounds__(256) void transpose_cvt(const float* __restrict__ in,
                                                     unsigned short* __restrict__ out, int n) {
  __shared__ float t[32][33];
  int bx = blockIdx.x * 32, by = blockIdx.y * 32;
  int tx = threadIdx.x, ty = threadIdx.y;
#pragma unroll
  for (int i = 0; i < 32; i += 8)
    t[ty + i][tx] = in[(ll)(by + ty + i) * n + bx + tx];
  __syncthreads();
#pragma unroll
  for (int i = 0; i < 32; i += 8)
    out[(ll)(bx + ty + i) * n + by + tx] = f2b(t[tx][ty + i]);
}

__global__ void concat2(const float* __restrict__ a, const float* __restrict__ b,
                        float* __restrict__ o, int n) {
  int i = blockIdx.x * 256 + threadIdx.x;
  if (i < n) { o[i] = a[i]; o[i + n] = b[i]; }
}

// ---------------- 128x128 2-phase kernel (round-3 verified) ----------------
// CAUSAL: 0 dense; 2 PV (Keff = brow+128).
template <int CAUSAL>
__global__ __launch_bounds__(256, 2) void gemm_tn(
    const unsigned short* __restrict__ A, const unsigned short* __restrict__ B,
    const float* __restrict__ bias, void* __restrict__ C,
    int K, int lda, int ldb, int ldc,
    ll strideA, ll strideB, ll strideC,
    float alpha, int c_is_bf16, int bias_row) {
  __shared__ unsigned short sA[2][128][64];
  __shared__ unsigned short sB[2][128][64];

  const int tid = threadIdx.x;
  const int w = tid >> 6, lane = tid & 63;
  const int bz = blockIdx.z;
  const unsigned short* Ab = A + (ll)bz * strideA;
  const unsigned short* Bb = B + (ll)bz * strideB;
  const int brow = blockIdx.y * 128, bcol = blockIdx.x * 128;
  const int wr = (w >> 1) * 64, wc = (w & 1) * 64;
  const int lr = lane & 15, lk = lane >> 4;

  const int Keff = (CAUSAL == 2) ? (brow + 128) : K;
  const int nt = Keff >> 6;

  f32x4 acc[4][4];
#pragma unroll
  for (int i = 0; i < 4; ++i)
#pragma unroll
    for (int n = 0; n < 4; ++n) acc[i][n] = (f32x4){0.f, 0.f, 0.f, 0.f};

  auto STAGE = [&](int buf, int kb) {
#pragma unroll
    for (int it = 0; it < 4; ++it) {
      const int chunk = it * 4 + w;
      const int slot = chunk * 64 + lane;
      const int row = slot >> 3;
      const int kg = (slot & 7) ^ (row & 7);
      gload16(Ab + (ll)(brow + row) * lda + kb + kg * 8, &sA[buf][0][0] + chunk * 512);
      gload16(Bb + (ll)(bcol + row) * ldb + kb + kg * 8, &sB[buf][0][0] + chunk * 512);
    }
  };

  auto COMPUTE = [&](int buf) {
#pragma unroll
    for (int kk = 0; kk < 64; kk += 32) {
      bf16x8 af[4], bfr[4];
      const int kgb = (kk >> 3) + lk;
      const int sw = (kgb ^ (lr & 7)) * 8;
#pragma unroll
      for (int i = 0; i < 4; ++i) af[i] = *(const bf16x8*)&sA[buf][wr + i * 16 + lr][sw];
#pragma unroll
      for (int n = 0; n < 4; ++n) bfr[n] = *(const bf16x8*)&sB[buf][wc + n * 16 + lr][sw];
#pragma unroll
      for (int i = 0; i < 4; ++i)
#pragma unroll
        for (int n = 0; n < 4; ++n)
          acc[i][n] = __builtin_amdgcn_mfma_f32_16x16x32_bf16(af[i], bfr[n], acc[i][n], 0, 0, 0);
    }
  };

  STAGE(0, 0);
  __syncthreads();
  int cur = 0;
  for (int t = 0; t < nt - 1; ++t) {
    STAGE(cur ^ 1, (t + 1) << 6);
    COMPUTE(cur);
    __syncthreads();
    cur ^= 1;
  }
  COMPUTE(cur);

  ll cbase = (ll)bz * strideC;
#pragma unroll
  for (int i = 0; i < 4; ++i) {
    int row = brow + wr + i * 16 + lk * 4;
#pragma unroll
    for (int n = 0; n < 4; ++n) {
      int col = bcol + wc + n * 16 + lr;
#pragma unroll
      for (int r = 0; r < 4; ++r) {
        float bvv = bias ? (bias_row ? bias[row + r] : bias[col]) : 0.0f;
        float v = (acc[i][n][r] + bvv) * alpha;
        ll idx = cbase + (ll)(row + r) * ldc + col;
        if (c_is_bf16) ((unsigned short*)C)[idx] = f2b(v);
        else ((float*)C)[idx] = v;
      }
    }
  }
}

// ---------------- 256x256 8-phase-style pipelined kernel ----------------
// BK=32. 8 waves (2M x 4N), per-wave output 128x64, acc[8][4].
// 4 LDS K-tile buffers (A 16KB + B 16KB each = 128KB). Stage lead = 2 tiles:
// during tile t's two phases we stage A(t+2) then B(t+2) into buf (t+2)&3
// (bufs in use: t, t+1 -> no conflict). Entry gate: vmcnt(4) = tile t landed,
// tile t+1's 4 loads still in flight. Never vmcnt(0) except the last tile.
// Per phase: {ds_read subtile, stage half-tile, barrier, setprio(1), 16 MFMA,
// setprio(0), barrier}. Swizzle: 16B slot s of row r holds k-group
// s ^ ((r>>1)&3) (involution; exact 2-way bank aliasing = free).
// CAUSAL: 0 dense; 1 scores (skip tiles with bcol > brow).
template <int CAUSAL>
__global__ __launch_bounds__(512, 2) void gemm8p(
    const unsigned short* __restrict__ A, const unsigned short* __restrict__ B,
    const float* __restrict__ bias, void* __restrict__ C,
    int K, int lda, int ldb, int ldc,
    ll strideA, ll strideB, ll strideC,
    float alpha, int c_is_bf16) {
  if (CAUSAL == 1 && blockIdx.x > blockIdx.y) return;

  __shared__ unsigned short smem[4 * 16384];  // buf: A[8192] | B[8192] shorts

  const int tid = threadIdx.x;
  const int wid = tid >> 6, lane = tid & 63;
  const int wm = wid >> 2, wn = wid & 3;
  const int lr = lane & 15, lk = lane >> 4;
  const int bz = blockIdx.z;
  const unsigned short* Ab = A + (ll)bz * strideA;
  const unsigned short* Bb = B + (ll)bz * strideB;
  const int brow = blockIdx.y * 256, bcol = blockIdx.x * 256;
  const int nt = K >> 5;

  f32x4 acc[8][4];
#pragma unroll
  for (int m = 0; m < 8; ++m)
#pragma unroll
    for (int n = 0; n < 4; ++n) acc[m][n] = (f32x4){0.f, 0.f, 0.f, 0.f};

  // Stage one 16KB half (A or B) of K-tile t: 2 gload16 per thread.
  auto STAGE_A = [&](int t) {
    unsigned short* lds = &smem[0] + (t & 3) * 16384;
    const int kb = t << 5;
#pragma unroll
    for (int h = 0; h < 2; ++h) {
      const int c = wid * 2 + h;             // chunk 0..15 (1KB each)
      const int row = c * 16 + (lane >> 2);  // 0..255
      const int kg = (lane & 3) ^ ((row >> 1) & 3);
      gload16(Ab + (ll)(brow + row) * lda + kb + kg * 8, lds + c * 512);
    }
  };
  auto STAGE_B = [&](int t) {
    unsigned short* lds = &smem[0] + (t & 3) * 16384 + 8192;
    const int kb = t << 5;
#pragma unroll
    for (int h = 0; h < 2; ++h) {
      const int c = wid * 2 + h;
      const int row = c * 16 + (lane >> 2);
      const int kg = (lane & 3) ^ ((row >> 1) & 3);
      gload16(Bb + (ll)(bcol + row) * ldb + kb + kg * 8, lds + c * 512);
    }
  };

  // Prologue: tiles 0 and 1 fully staged (8 loads in flight).
  STAGE_A(0); STAGE_B(0);
  STAGE_A(1); STAGE_B(1);

  for (int t = 0; t < nt; ++t) {
    if (t < nt - 1) asm volatile("s_waitcnt vmcnt(4)" ::: "memory");
    else            asm volatile("s_waitcnt vmcnt(0)" ::: "memory");
    __builtin_amdgcn_s_barrier();  // tile t resident for ALL waves

    const unsigned short* lds = &smem[0] + (t & 3) * 16384;
    bf16x8 bfrag[4], afrag[4];

    // ---- phase 0: b[0..3] + a[0..3]; stage A(t+2); MFMA m=0..3 ----
#pragma unroll
    for (int n = 0; n < 4; ++n) {
      const int row = wn * 64 + n * 16 + lr;
      const int slot = lk ^ ((row >> 1) & 3);
      bfrag[n] = *(const bf16x8*)(lds + 8192 + row * 32 + slot * 8);
    }
#pragma unroll
    for (int m = 0; m < 4; ++m) {
      const int row = wm * 128 + m * 16 + lr;
      const int slot = lk ^ ((row >> 1) & 3);
      afrag[m] = *(const bf16x8*)(lds + row * 32 + slot * 8);
    }
    if (t + 2 < nt) STAGE_A(t + 2);
    __builtin_amdgcn_s_barrier();
    __builtin_amdgcn_s_setprio(1);
#pragma unroll
    for (int m = 0; m < 4; ++m)
#pragma unroll
      for (int n = 0; n < 4; ++n)
        acc[m][n] = __builtin_amdgcn_mfma_f32_16x16x32_bf16(afrag[m], bfrag[n], acc[m][n], 0, 0, 0);
    __builtin_amdgcn_s_setprio(0);
    __builtin_amdgcn_s_barrier();

    // ---- phase 1: a[4..7]; stage B(t+2); MFMA m=4..7 ----
#pragma unroll
    for (int m = 0; m < 4; ++m) {
      const int row = wm * 128 + (m + 4) * 16 + lr;
      const int slot = lk ^ ((row >> 1) & 3);
      afrag[m] = *(const bf16x8*)(lds + row * 32 + slot * 8);
    }
    if (t + 2 < nt) STAGE_B(t + 2);
    __builtin_amdgcn_s_barrier();
    __builtin_amdgcn_s_setprio(1);
#pragma unroll
    for (int m = 0; m < 4; ++m)
#pragma unroll
      for (int n = 0; n < 4; ++n)
        acc[m + 4][n] = __builtin_amdgcn_mfma_f32_16x16x32_bf16(afrag[m], bfrag[n], acc[m + 4][n], 0, 0, 0);
    __builtin_amdgcn_s_setprio(0);
    // next-tile entry barrier follows; no extra barrier needed here
  }

  ll cbase = (ll)bz * strideC;
#pragma unroll
  for (int m = 0; m < 8; ++m) {
    const int row0 = brow + wm * 128 + m * 16 + lk * 4;
#pragma unroll
    for (int n = 0; n < 4; ++n) {
      const int col = bcol + wn * 64 + n * 16 + lr;
#pragma unroll
      for (int r = 0; r < 4; ++r) {
        float bvv = bias ? bias[col] : 0.0f;
        float v = (acc[m][n][r] + bvv) * alpha;
        ll idx = cbase + (ll)(row0 + r) * ldc + col;
        if (c_is_bf16) ((unsigned short*)C)[idx] = f2b(v);
        else ((float*)C)[idx] = v;
      }
    }
  }
}

// One-pass causal softmax for rows of exactly 2048 bf16.
__global__ __launch_bounds__(256) void softmax_row2048(unsigned short* __restrict__ S) {
  const int r = blockIdx.x, b = blockIdx.y;
  unsigned short* row = S + ((ll)b * 2048 + r) * 2048;
  const int tid = threadIdx.x;
  const int i0 = tid * 8;
  __shared__ float red[4];

  u16x8 v = *(const u16x8*)(row + i0);
  float f[8];
  float m = -3.0e38f;
#pragma unroll
  for (int j = 0; j < 8; ++j) {
    f[j] = (i0 + j <= r) ? b2f(v[j]) : -3.0e38f;
    m = fmaxf(m, f[j]);
  }
#pragma unroll
  for (int o = 1; o < 64; o <<= 1) m = fmaxf(m, __shfl_xor(m, o, 64));
  if ((tid & 63) == 0) red[tid >> 6] = m;
  __syncthreads();
  m = fmaxf(fmaxf(red[0], red[1]), fmaxf(red[2], red[3]));
  __syncthreads();

  float e[8];
  float s = 0.0f;
#pragma unroll
  for (int j = 0; j < 8; ++j) {
    e[j] = (i0 + j <= r) ? __expf(f[j] - m) : 0.0f;
    s += e[j];
  }
#pragma unroll
  for (int o = 1; o < 64; o <<= 1) s += __shfl_xor(s, o, 64);
  if ((tid & 63) == 0) red[tid >> 6] = s;
  __syncthreads();
  s = red[0] + red[1] + red[2] + red[3];
  float inv = 1.0f / s;
  u16x8 o8;
#pragma unroll
  for (int j = 0; j < 8; ++j) o8[j] = f2b(e[j] * inv);
  *(u16x8*)(row + i0) = o8;
}

extern "C" void kernel_launch(void* const* d_in, const int* in_sizes, int n_in,
                              void* d_out, int out_size, void* d_ws, size_t ws_size,
                              hipStream_t stream) {
  const float* x  = (const float*)d_in[0];
  const float* Wq = (const float*)d_in[1];
  const float* bq = (const float*)d_in[2];
  const float* Wk = (const float*)d_in[3];
  const float* bk = (const float*)d_in[4];
  const float* Wv = (const float*)d_in[5];
  const float* bv = (const float*)d_in[6];
  const float* Wo = (const float*)d_in[7];
  const float* bo = (const float*)d_in[8];

  const int B = 4, S = 2048, D = 1024;
  const ll MS = (ll)B * S;  // 8192

  char* p = (char*)d_ws;
  unsigned short* xb   = (unsigned short*)p; p += MS * D * 2;
  unsigned short* Wqkt = (unsigned short*)p; p += (ll)2 * D * D * 2;  // [Wq^T; Wk^T]
  unsigned short* Wvt  = (unsigned short*)p; p += (ll)D * D * 2;
  unsigned short* Wot  = (unsigned short*)p; p += (ll)D * D * 2;
  float*          bqkc = (float*)p;          p += 2 * D * 4;
  unsigned short* QKc  = (unsigned short*)p; p += MS * 2 * D * 2;     // [Q | K]
  unsigned short* Vt   = (unsigned short*)p; p += (ll)D * MS * 2;     // V^T
  unsigned short* Sm   = (unsigned short*)p; p += (ll)B * S * S * 2;
  unsigned short* At   = (unsigned short*)p; p += MS * D * 2;

  dim3 blk(256);
  dim3 blk512(512);
  dim3 tblk(32, 8);

  cvt_f32_bf16<<<dim3(4096), blk, 0, stream>>>(x, xb, MS * D);
  transpose_cvt<<<dim3(32, 32), tblk, 0, stream>>>(Wq, Wqkt, D);
  transpose_cvt<<<dim3(32, 32), tblk, 0, stream>>>(Wk, Wqkt + (ll)D * D, D);
  transpose_cvt<<<dim3(32, 32), tblk, 0, stream>>>(Wv, Wvt, D);
  transpose_cvt<<<dim3(32, 32), tblk, 0, stream>>>(Wo, Wot, D);
  concat2<<<dim3(4), blk, 0, stream>>>(bq, bk, bqkc, D);

  // Fused Q|K projection (8-phase, grid 256 blocks fills all CUs)
  gemm8p<0><<<dim3(8, 32, 1), blk512, 0, stream>>>(
      xb, Wqkt, bqkc, QKc, D, D, D, 2 * D, 0, 0, 0, 1.0f, 1);

  // V^T [1024, 8192] = Wv^T @ x^T + bv (row bias) — 2-phase, grid 512
  gemm_tn<0><<<dim3(64, 8, 1), blk, 0, stream>>>(
      Wvt, xb, bv, Vt, D, D, D, (int)MS, 0, 0, 0, 1.0f, 1, 1);

  // Scores: Sm[b] = (Q_b @ K_b^T)/32 (8-phase, 144 blocks after causal skip)
  gemm8p<1><<<dim3(8, 8, 4), blk512, 0, stream>>>(
      QKc, QKc + D, nullptr, Sm, D, 2 * D, 2 * D, S,
      (ll)S * 2 * D, (ll)S * 2 * D, (ll)S * S, 0.03125f, 1);

  softmax_row2048<<<dim3(S, B), blk, 0, stream>>>(Sm);

  // PV: At[b] = P_b @ V_b, Keff = brow+128 (2-phase, grid 512)
  gemm_tn<2><<<dim3(8, 16, 4), blk, 0, stream>>>(
      Sm, Vt, nullptr, At, S, S, (int)MS, D,
      (ll)S * S, (ll)S, (ll)S * D, 1.0f, 1, 0);

  // out = At @ Wo + bo (f32) — 2-phase, grid 512
  gemm_tn<0><<<dim3(8, 64, 1), blk, 0, stream>>>(
      At, Wot, bo, d_out, D, D, D, D, 0, 0, 0, 1.0f, 0, 0);
}

// Round 12
// 328.740 us; speedup vs baseline: 1.2391x; 1.0363x over previous
//
#include <hip/hip_runtime.h>
#include <hip/hip_bf16.h>

// SimpleMHA. Two GEMM kernels:
//  - gemm8p: 256x256 tile, BK=32, counted-vmcnt pipeline (r7-verified) for
//    QK-proj (256 blocks) and scores (144 live blocks).
//  - gemmp: 128x256 tile, 3-buffer counted-vmcnt pipeline, 72KB LDS ->
//    2 blocks/CU, for V^T / PV / out-proj (grids 256).
// B=4, S=2048, D=1024, scale 1/32 in the score epilogue.

typedef __attribute__((ext_vector_type(8))) __bf16 bf16x8;
typedef __attribute__((ext_vector_type(4))) float f32x4;
typedef __attribute__((ext_vector_type(8))) unsigned short u16x8;
typedef __attribute__((ext_vector_type(4))) float float4v;
typedef long long ll;

static __device__ __forceinline__ unsigned short f2b(float f) {
  unsigned int u = __float_as_uint(f);
  u += 0x7fffu + ((u >> 16) & 1u);
  return (unsigned short)(u >> 16);
}
static __device__ __forceinline__ float b2f(unsigned short b) {
  return __uint_as_float(((unsigned int)b) << 16);
}

static __device__ __forceinline__ void gload16(const unsigned short* g, unsigned short* l) {
  // 16B direct global->LDS. LDS dest = wave-uniform base + lane*16 (HW rule).
  __builtin_amdgcn_global_load_lds(
      (const __attribute__((address_space(1))) void*)g,
      (__attribute__((address_space(3))) void*)l, 16, 0, 0);
}

__global__ __launch_bounds__(256) void cvt_f32_bf16(const float* __restrict__ in,
                                                    unsigned short* __restrict__ out,
                                                    long long n) {
  long long i = ((long long)blockIdx.x * 256 + threadIdx.x) * 8;
  if (i + 8 > n) return;
  float4v a = *(const float4v*)(in + i);
  float4v b = *(const float4v*)(in + i + 4);
  u16x8 o;
  o[0] = f2b(a[0]); o[1] = f2b(a[1]); o[2] = f2b(a[2]); o[3] = f2b(a[3]);
  o[4] = f2b(b[0]); o[5] = f2b(b[1]); o[6] = f2b(b[2]); o[7] = f2b(b[3]);
  *(u16x8*)(out + i) = o;
}

// out[c][r] = bf16(in[r][c]) for n x n f32 input. Block (32,8), 32x32 tiles.
__global__ __launch_bounds__(256) void transpose_cvt(const float* __restrict__ in,
                                                     unsigned short* __restrict__ out, int n) {
  __shared__ float t[32][33];
  int bx = blockIdx.x * 32, by = blockIdx.y * 32;
  int tx = threadIdx.x, ty = threadIdx.y;
#pragma unroll
  for (int i = 0; i < 32; i += 8)
    t[ty + i][tx] = in[(ll)(by + ty + i) * n + bx + tx];
  __syncthreads();
#pragma unroll
  for (int i = 0; i < 32; i += 8)
    out[(ll)(bx + ty + i) * n + by + tx] = f2b(t[tx][ty + i]);
}

__global__ void concat2(const float* __restrict__ a, const float* __restrict__ b,
                        float* __restrict__ o, int n) {
  int i = blockIdx.x * 256 + threadIdx.x;
  if (i < n) { o[i] = a[i]; o[i + n] = b[i]; }
}

// ---------------- 256x256 pipelined kernel (round-7 verified) ----------------
// BK=32. 8 waves (2M x 4N), per-wave 128x64, acc[8][4]. 4 LDS buffers (128KB).
// Entry gate vmcnt(4); stage A(t+2) in ph0, B(t+2) in ph1; vmcnt(0) last tile.
// Swizzle: slot s of row r holds k-group s^((r>>1)&3), both-sides involution.
// CAUSAL: 0 dense; 1 scores (skip tiles with bcol > brow).
template <int CAUSAL>
__global__ __launch_bounds__(512, 2) void gemm8p(
    const unsigned short* __restrict__ A, const unsigned short* __restrict__ B,
    const float* __restrict__ bias, void* __restrict__ C,
    int K, int lda, int ldb, int ldc,
    ll strideA, ll strideB, ll strideC,
    float alpha, int c_is_bf16) {
  if (CAUSAL == 1 && blockIdx.x > blockIdx.y) return;

  __shared__ unsigned short smem[4 * 16384];  // buf: A[8192] | B[8192] shorts

  const int tid = threadIdx.x;
  const int wid = tid >> 6, lane = tid & 63;
  const int wm = wid >> 2, wn = wid & 3;
  const int lr = lane & 15, lk = lane >> 4;
  const int bz = blockIdx.z;
  const unsigned short* Ab = A + (ll)bz * strideA;
  const unsigned short* Bb = B + (ll)bz * strideB;
  const int brow = blockIdx.y * 256, bcol = blockIdx.x * 256;
  const int nt = K >> 5;

  f32x4 acc[8][4];
#pragma unroll
  for (int m = 0; m < 8; ++m)
#pragma unroll
    for (int n = 0; n < 4; ++n) acc[m][n] = (f32x4){0.f, 0.f, 0.f, 0.f};

  auto STAGE_A = [&](int t) {
    unsigned short* lds = &smem[0] + (t & 3) * 16384;
    const int kb = t << 5;
#pragma unroll
    for (int h = 0; h < 2; ++h) {
      const int c = wid * 2 + h;
      const int row = c * 16 + (lane >> 2);
      const int kg = (lane & 3) ^ ((row >> 1) & 3);
      gload16(Ab + (ll)(brow + row) * lda + kb + kg * 8, lds + c * 512);
    }
  };
  auto STAGE_B = [&](int t) {
    unsigned short* lds = &smem[0] + (t & 3) * 16384 + 8192;
    const int kb = t << 5;
#pragma unroll
    for (int h = 0; h < 2; ++h) {
      const int c = wid * 2 + h;
      const int row = c * 16 + (lane >> 2);
      const int kg = (lane & 3) ^ ((row >> 1) & 3);
      gload16(Bb + (ll)(bcol + row) * ldb + kb + kg * 8, lds + c * 512);
    }
  };

  STAGE_A(0); STAGE_B(0);
  STAGE_A(1); STAGE_B(1);

  for (int t = 0; t < nt; ++t) {
    if (t < nt - 1) asm volatile("s_waitcnt vmcnt(4)" ::: "memory");
    else            asm volatile("s_waitcnt vmcnt(0)" ::: "memory");
    __builtin_amdgcn_s_barrier();

    const unsigned short* lds = &smem[0] + (t & 3) * 16384;
    bf16x8 bfrag[4], afrag[4];

#pragma unroll
    for (int n = 0; n < 4; ++n) {
      const int row = wn * 64 + n * 16 + lr;
      const int slot = lk ^ ((row >> 1) & 3);
      bfrag[n] = *(const bf16x8*)(lds + 8192 + row * 32 + slot * 8);
    }
#pragma unroll
    for (int m = 0; m < 4; ++m) {
      const int row = wm * 128 + m * 16 + lr;
      const int slot = lk ^ ((row >> 1) & 3);
      afrag[m] = *(const bf16x8*)(lds + row * 32 + slot * 8);
    }
    if (t + 2 < nt) STAGE_A(t + 2);
    __builtin_amdgcn_s_barrier();
    __builtin_amdgcn_s_setprio(1);
#pragma unroll
    for (int m = 0; m < 4; ++m)
#pragma unroll
      for (int n = 0; n < 4; ++n)
        acc[m][n] = __builtin_amdgcn_mfma_f32_16x16x32_bf16(afrag[m], bfrag[n], acc[m][n], 0, 0, 0);
    __builtin_amdgcn_s_setprio(0);
    __builtin_amdgcn_s_barrier();

#pragma unroll
    for (int m = 0; m < 4; ++m) {
      const int row = wm * 128 + (m + 4) * 16 + lr;
      const int slot = lk ^ ((row >> 1) & 3);
      afrag[m] = *(const bf16x8*)(lds + row * 32 + slot * 8);
    }
    if (t + 2 < nt) STAGE_B(t + 2);
    __builtin_amdgcn_s_barrier();
    __builtin_amdgcn_s_setprio(1);
#pragma unroll
    for (int m = 0; m < 4; ++m)
#pragma unroll
      for (int n = 0; n < 4; ++n)
        acc[m + 4][n] = __builtin_amdgcn_mfma_f32_16x16x32_bf16(afrag[m], bfrag[n], acc[m + 4][n], 0, 0, 0);
    __builtin_amdgcn_s_setprio(0);
  }

  ll cbase = (ll)bz * strideC;
#pragma unroll
  for (int m = 0; m < 8; ++m) {
    const int row0 = brow + wm * 128 + m * 16 + lk * 4;
#pragma unroll
    for (int n = 0; n < 4; ++n) {
      const int col = bcol + wn * 64 + n * 16 + lr;
#pragma unroll
      for (int r = 0; r < 4; ++r) {
        float bvv = bias ? bias[col] : 0.0f;
        float v = (acc[m][n][r] + bvv) * alpha;
        ll idx = cbase + (ll)(row0 + r) * ldc + col;
        if (c_is_bf16) ((unsigned short*)C)[idx] = f2b(v);
        else ((float*)C)[idx] = v;
      }
    }
  }
}

// ---------------- 128x256 pipelined GEMM (3-buffer, 2 blocks/CU) ----------------
// 8 waves as 2M x 4N, per-wave 64x64 output, acc[4][4].
// Ledger: 3 gload16/thread/tile (1 A + 2 B); prologue 6 outstanding; entry
// vmcnt(3); ph0 stages A(t+2), ph1 stages B(t+2); vmcnt(0) only last tile.
// CAUSAL: 0 dense; 2 PV (Keff = brow+128).
template <int CAUSAL>
__global__ __launch_bounds__(512, 4) void gemmp(
    const unsigned short* __restrict__ A, const unsigned short* __restrict__ B,
    const float* __restrict__ bias, void* __restrict__ C,
    int K, int lda, int ldb, int ldc,
    ll strideA, ll strideB, ll strideC,
    float alpha, int c_is_bf16, int bias_row) {
  __shared__ unsigned short smem[3 * 12288];  // buf: A[4096] | B[8192] shorts

  const int tid = threadIdx.x;
  const int wid = tid >> 6, lane = tid & 63;
  const int wm = wid >> 2, wn = wid & 3;  // 2M x 4N
  const int lr = lane & 15, lk = lane >> 4;
  const int bz = blockIdx.z;
  const unsigned short* Ab = A + (ll)bz * strideA;
  const unsigned short* Bb = B + (ll)bz * strideB;
  const int brow = blockIdx.y * 128, bcol = blockIdx.x * 256;

  const int Keff = (CAUSAL == 2) ? (brow + 128) : K;
  const int nt = Keff >> 5;  // >= 4 always here

  f32x4 acc[4][4];
#pragma unroll
  for (int m = 0; m < 4; ++m)
#pragma unroll
    for (int n = 0; n < 4; ++n) acc[m][n] = (f32x4){0.f, 0.f, 0.f, 0.f};

  auto STAGE_A = [&](int t, int b) {
    unsigned short* lds = &smem[0] + b * 12288 + wid * 512;
    const int kb = t << 5;
    const int row = wid * 16 + (lane >> 2);         // 0..127
    const int kg = (lane & 3) ^ ((row >> 1) & 3);
    gload16(Ab + (ll)(brow + row) * lda + kb + kg * 8, lds);
  };
  auto STAGE_B = [&](int t, int b) {
    unsigned short* lds0 = &smem[0] + b * 12288 + 4096;
    const int kb = t << 5;
#pragma unroll
    for (int h = 0; h < 2; ++h) {
      const int c = wid * 2 + h;                    // chunk 0..15 (1KB)
      const int row = c * 16 + (lane >> 2);         // 0..255
      const int kg = (lane & 3) ^ ((row >> 1) & 3);
      gload16(Bb + (ll)(bcol + row) * ldb + kb + kg * 8, lds0 + c * 512);
    }
  };

  STAGE_A(0, 0); STAGE_B(0, 0);
  STAGE_A(1, 1); STAGE_B(1, 1);

  int cur = 0;
  for (int t = 0; t < nt; ++t) {
    if (t < nt - 1) asm volatile("s_waitcnt vmcnt(3)" ::: "memory");
    else            asm volatile("s_waitcnt vmcnt(0)" ::: "memory");
    __builtin_amdgcn_s_barrier();

    const unsigned short* ldsA = &smem[0] + cur * 12288;
    const unsigned short* ldsB = ldsA + 4096;
    int sbuf = cur + 2; if (sbuf >= 3) sbuf -= 3;
    bf16x8 bfrag[4], afrag[4];

    // phase 0: read B n=0..3 + A m=0..1; stage A(t+2); MFMA m=0..1
#pragma unroll
    for (int n = 0; n < 4; ++n) {
      const int row = wn * 64 + n * 16 + lr;
      const int slot = lk ^ ((row >> 1) & 3);
      bfrag[n] = *(const bf16x8*)(ldsB + row * 32 + slot * 8);
    }
#pragma unroll
    for (int m = 0; m < 2; ++m) {
      const int row = wm * 64 + m * 16 + lr;
      const int slot = lk ^ ((row >> 1) & 3);
      afrag[m] = *(const bf16x8*)(ldsA + row * 32 + slot * 8);
    }
    if (t + 2 < nt) STAGE_A(t + 2, sbuf);
    __builtin_amdgcn_s_barrier();
    __builtin_amdgcn_s_setprio(1);
#pragma unroll
    for (int m = 0; m < 2; ++m)
#pragma unroll
      for (int n = 0; n < 4; ++n)
        acc[m][n] = __builtin_amdgcn_mfma_f32_16x16x32_bf16(afrag[m], bfrag[n], acc[m][n], 0, 0, 0);
    __builtin_amdgcn_s_setprio(0);
    __builtin_amdgcn_s_barrier();

    // phase 1: read A m=2..3; stage B(t+2); MFMA m=2..3
#pragma unroll
    for (int m = 2; m < 4; ++m) {
      const int row = wm * 64 + m * 16 + lr;
      const int slot = lk ^ ((row >> 1) & 3);
      afrag[m] = *(const bf16x8*)(ldsA + row * 32 + slot * 8);
    }
    if (t + 2 < nt) STAGE_B(t + 2, sbuf);
    __builtin_amdgcn_s_barrier();
    __builtin_amdgcn_s_setprio(1);
#pragma unroll
    for (int m = 2; m < 4; ++m)
#pragma unroll
      for (int n = 0; n < 4; ++n)
        acc[m][n] = __builtin_amdgcn_mfma_f32_16x16x32_bf16(afrag[m], bfrag[n], acc[m][n], 0, 0, 0);
    __builtin_amdgcn_s_setprio(0);

    cur = (cur == 2) ? 0 : cur + 1;
  }

  // C/D layout: col=lane&15, row=(lane>>4)*4+reg (m89-verified)
  ll cbase = (ll)bz * strideC;
#pragma unroll
  for (int m = 0; m < 4; ++m) {
    const int row0 = brow + wm * 64 + m * 16 + lk * 4;
#pragma unroll
    for (int n = 0; n < 4; ++n) {
      const int col = bcol + wn * 64 + n * 16 + lr;
#pragma unroll
      for (int r = 0; r < 4; ++r) {
        float bvv = bias ? (bias_row ? bias[row0 + r] : bias[col]) : 0.0f;
        float v = (acc[m][n][r] + bvv) * alpha;
        ll idx = cbase + (ll)(row0 + r) * ldc + col;
        if (c_is_bf16) ((unsigned short*)C)[idx] = f2b(v);
        else ((float*)C)[idx] = v;
      }
    }
  }
}

// One-pass causal softmax for rows of exactly 2048 bf16.
__global__ __launch_bounds__(256) void softmax_row2048(unsigned short* __restrict__ S) {
  const int r = blockIdx.x, b = blockIdx.y;
  unsigned short* row = S + ((ll)b * 2048 + r) * 2048;
  const int tid = threadIdx.x;
  const int i0 = tid * 8;
  __shared__ float red[4];

  u16x8 v = *(const u16x8*)(row + i0);
  float f[8];
  float m = -3.0e38f;
#pragma unroll
  for (int j = 0; j < 8; ++j) {
    f[j] = (i0 + j <= r) ? b2f(v[j]) : -3.0e38f;
    m = fmaxf(m, f[j]);
  }
#pragma unroll
  for (int o = 1; o < 64; o <<= 1) m = fmaxf(m, __shfl_xor(m, o, 64));
  if ((tid & 63) == 0) red[tid >> 6] = m;
  __syncthreads();
  m = fmaxf(fmaxf(red[0], red[1]), fmaxf(red[2], red[3]));
  __syncthreads();

  float e[8];
  float s = 0.0f;
#pragma unroll
  for (int j = 0; j < 8; ++j) {
    e[j] = (i0 + j <= r) ? __expf(f[j] - m) : 0.0f;
    s += e[j];
  }
#pragma unroll
  for (int o = 1; o < 64; o <<= 1) s += __shfl_xor(s, o, 64);
  if ((tid & 63) == 0) red[tid >> 6] = s;
  __syncthreads();
  s = red[0] + red[1] + red[2] + red[3];
  float inv = 1.0f / s;
  u16x8 o8;
#pragma unroll
  for (int j = 0; j < 8; ++j) o8[j] = f2b(e[j] * inv);
  *(u16x8*)(row + i0) = o8;
}

extern "C" void kernel_launch(void* const* d_in, const int* in_sizes, int n_in,
                              void* d_out, int out_size, void* d_ws, size_t ws_size,
                              hipStream_t stream) {
  const float* x  = (const float*)d_in[0];
  const float* Wq = (const float*)d_in[1];
  const float* bq = (const float*)d_in[2];
  const float* Wk = (const float*)d_in[3];
  const float* bk = (const float*)d_in[4];
  const float* Wv = (const float*)d_in[5];
  const float* bv = (const float*)d_in[6];
  const float* Wo = (const float*)d_in[7];
  const float* bo = (const float*)d_in[8];

  const int B = 4, S = 2048, D = 1024;
  const ll MS = (ll)B * S;  // 8192

  char* p = (char*)d_ws;
  unsigned short* xb   = (unsigned short*)p; p += MS * D * 2;
  unsigned short* Wqkt = (unsigned short*)p; p += (ll)2 * D * D * 2;  // [Wq^T; Wk^T]
  unsigned short* Wvt  = (unsigned short*)p; p += (ll)D * D * 2;
  unsigned short* Wot  = (unsigned short*)p; p += (ll)D * D * 2;
  float*          bqkc = (float*)p;          p += 2 * D * 4;
  unsigned short* QKc  = (unsigned short*)p; p += MS * 2 * D * 2;     // [Q | K]
  unsigned short* Vt   = (unsigned short*)p; p += (ll)D * MS * 2;     // V^T
  unsigned short* Sm   = (unsigned short*)p; p += (ll)B * S * S * 2;
  unsigned short* At   = (unsigned short*)p; p += MS * D * 2;

  dim3 blk(256);
  dim3 blk512(512);
  dim3 tblk(32, 8);

  cvt_f32_bf16<<<dim3(4096), blk, 0, stream>>>(x, xb, MS * D);
  transpose_cvt<<<dim3(32, 32), tblk, 0, stream>>>(Wq, Wqkt, D);
  transpose_cvt<<<dim3(32, 32), tblk, 0, stream>>>(Wk, Wqkt + (ll)D * D, D);
  transpose_cvt<<<dim3(32, 32), tblk, 0, stream>>>(Wv, Wvt, D);
  transpose_cvt<<<dim3(32, 32), tblk, 0, stream>>>(Wo, Wot, D);
  concat2<<<dim3(4), blk, 0, stream>>>(bq, bk, bqkc, D);

  // Fused Q|K projection (gemm8p, verified r7): 256 blocks
  gemm8p<0><<<dim3(8, 32, 1), blk512, 0, stream>>>(
      xb, Wqkt, bqkc, QKc, D, D, D, 2 * D, 0, 0, 0, 1.0f, 1);

  // V^T [1024,8192] = Wv^T @ x^T + bv (row bias) — gemmp, 256 blocks
  gemmp<0><<<dim3(32, 8, 1), blk512, 0, stream>>>(
      Wvt, xb, bv, Vt, D, D, D, (int)MS, 0, 0, 0, 1.0f, 1, 1);

  // Scores: Sm[b] = (Q_b @ K_b^T)/32 (gemm8p, verified r7): 144 live blocks
  gemm8p<1><<<dim3(8, 8, 4), blk512, 0, stream>>>(
      QKc, QKc + D, nullptr, Sm, D, 2 * D, 2 * D, S,
      (ll)S * 2 * D, (ll)S * 2 * D, (ll)S * S, 0.03125f, 1);

  softmax_row2048<<<dim3(S, B), blk, 0, stream>>>(Sm);

  // PV: At[b] = P_b @ V_b, Keff = brow+128 — gemmp, 256 blocks
  gemmp<2><<<dim3(4, 16, 4), blk512, 0, stream>>>(
      Sm, Vt, nullptr, At, S, S, (int)MS, D,
      (ll)S * S, (ll)S, (ll)S * D, 1.0f, 1, 0);

  // out = At @ Wo + bo (f32) — gemmp, 256 blocks
  gemmp<0><<<dim3(4, 64, 1), blk512, 0, stream>>>(
      At, Wot, bo, d_out, D, D, D, D, 0, 0, 0, 1.0f, 0, 0);
}